// Round 8
// baseline (156.972 us; speedup 1.0000x reference)
//
#include <hip/hip_runtime.h>
#include <hip/hip_fp16.h>

#define B_    4
#define C_    192
#define N_    8192
#define K_    16
#define O_    192
#define TWOC_ 384
#define BN_   (B_ * N_)
#define NSL_  48   // 4-channel slices

typedef __attribute__((ext_vector_type(8))) _Float16 half8;
typedef __attribute__((ext_vector_type(4))) _Float16 half4v;
typedef __attribute__((ext_vector_type(4))) float floatx4;
typedef __attribute__((ext_vector_type(4))) float fvec4;
typedef __attribute__((ext_vector_type(4))) int   ivec4;
typedef __attribute__((ext_vector_type(4))) unsigned int uvec4;
typedef __attribute__((ext_vector_type(2))) unsigned int uvec2;

// ---------------- K1: prep ----------------
// blocks 0..6143: 32x32 transpose tiles -> xt[b,n,192] fp16  AND  xg[b,48,N,4] fp16
// (slice-major node-contiguous 8B units for the LDS gather). 6144..6161: W -> fp16.
__global__ __launch_bounds__(256) void k_prep(const float* __restrict__ x,
                                              const float* __restrict__ W,
                                              unsigned short* __restrict__ xt,
                                              unsigned short* __restrict__ xg,
                                              unsigned short* __restrict__ Wb) {
    int bid = blockIdx.x;
    int tid = threadIdx.x;

    if (bid >= 6144) {
        int base = ((bid - 6144) * 256 + tid) * 16;
        union { unsigned short u[16]; uvec4 v[2]; } o;
#pragma unroll
        for (int q = 0; q < 16; q += 4) {
            fvec4 f = __builtin_nontemporal_load((const fvec4*)(W + base + q));
            union { _Float16 h; unsigned short s; } c;
            c.h = (_Float16)f.x; o.u[q + 0] = c.s;
            c.h = (_Float16)f.y; o.u[q + 1] = c.s;
            c.h = (_Float16)f.z; o.u[q + 2] = c.s;
            c.h = (_Float16)f.w; o.u[q + 3] = c.s;
        }
        *(uvec4*)(Wb + base)     = o.v[0];
        *(uvec4*)(Wb + base + 8) = o.v[1];
        return;
    }

    __shared__ float tile[32][33];
    int xcd  = bid & 7;
    int b    = xcd >> 1;
    int half = xcd & 1;
    int slot = bid >> 3;
    int ct   = slot >> 7;                // 0..5  (c0 = ct*32 -> slices ct*8 .. ct*8+7)
    int nt   = half * 128 + (slot & 127);
    int c0 = ct * 32, n0 = nt * 32;

    int cc  = tid >> 3;
    int nn4 = (tid & 7) * 4;
    const float* xp = x + ((size_t)b * C_ + c0 + cc) * N_ + n0 + nn4;
    fvec4 v = __builtin_nontemporal_load((const fvec4*)xp);
    tile[nn4 + 0][cc] = v.x;
    tile[nn4 + 1][cc] = v.y;
    tile[nn4 + 2][cc] = v.z;
    tile[nn4 + 3][cc] = v.w;
    __syncthreads();

    // xt[b,n,192]
#pragma unroll
    for (int i = 0; i < 2; i++) {
        int id  = i * 256 + tid;
        int row = id >> 4;
        int ch2 = id & 15;
        union { _Float16 h[2]; unsigned int u; } p;
        p.h[0] = (_Float16)tile[row][ch2 * 2];
        p.h[1] = (_Float16)tile[row][ch2 * 2 + 1];
        *(unsigned int*)(xt + ((size_t)b * N_ + n0 + row) * C_ + c0 + ch2 * 2) = p.u;
    }

    // xg[b, slice, n, 4ch]: 8 slices x 32 rows, one 8B store per thread (coalesced in n)
    {
        int sl  = tid >> 5;              // 0..7
        int row = tid & 31;              // 0..31
        union { _Float16 h[4]; uvec2 u; } p;
#pragma unroll
        for (int c = 0; c < 4; c++) p.h[c] = (_Float16)tile[row][sl * 4 + c];
        *(uvec2*)(xg + ((size_t)(b * NSL_ + ct * 8 + sl) * N_ + n0 + row) * 4) = p.u;
    }
}

// ---------------- KG: channel-sliced LDS gather, b64 reads ----------------
// 384 blocks x 256 thr = (8 XCD-pinned (b, n-half)) x 48 slices.
// Stage slice (all 8192 nodes x 4ch = 64 KiB, node-major 8B) -> LDS, then
// gather 4096 nodes x 16 k x 2 rows via ds_read_b64, packed fp16 max-reduce.
__global__ __launch_bounds__(256) void k_gather(const unsigned short* __restrict__ xg,
                                                const int* __restrict__ eidx,
                                                unsigned short* __restrict__ rt) {
    __shared__ uvec2 lds2[N_];           // 64 KiB

    int bid = blockIdx.x;                // 384
    int xcd = bid & 7;
    int b   = xcd >> 1;
    int nh  = xcd & 1;
    int s   = bid >> 3;                  // 0..47
    int tid = threadIdx.x;

    // ---- stage: coalesced 16B loads, conflict-free b128 LDS writes ----
    const unsigned short* src = xg + (size_t)(b * NSL_ + s) * N_ * 4;
#pragma unroll
    for (int i = 0; i < 16; i++) {
        int idx = i * 256 + tid;         // 2-node unit
        uvec4 v = *(const uvec4*)(src + (size_t)idx * 8);
        *(uvec4*)&lds2[idx * 2] = v;
    }
    __syncthreads();

    int nbase = nh * 4096;
    const int* e0 = eidx + (size_t)b * N_ * K_;
    const int* e1 = e0 + (size_t)BN_ * K_;
    unsigned short* rto = rt + (size_t)b * N_ * C_ + s * 4;

#pragma unroll 2
    for (int nn = 0; nn < 16; nn++) {
        int n = nbase + tid * 16 + nn;   // thread-contiguous: node's 64B eidx row L1-resident
        const int* ej = e0 + (size_t)n * K_;
        const int* ei = e1 + (size_t)n * K_;
        ivec4 J[4], I[4];
#pragma unroll
        for (int q = 0; q < 4; q++) {
            J[q] = *(const ivec4*)(ej + q * 4);
            I[q] = *(const ivec4*)(ei + q * 4);
        }
        half4v m;
#pragma unroll
        for (int q = 0; q < 4; q++)
#pragma unroll
            for (int e = 0; e < 4; e++) {
                union { uvec2 u; half4v h; } jv, iv;
                jv.u = lds2[J[q][e]];
                iv.u = lds2[I[q][e]];
                half4v d = jv.h - iv.h;
                m = (q == 0 && e == 0) ? d : __builtin_elementwise_max(m, d);
            }
        union { half4v h; uvec2 u; } o;
        o.h = m;
        *(uvec2*)(rto + (size_t)n * C_) = o.u;
    }
}

// ---------------- KC: 1x1 conv GEMM (fp16 MFMA), swizzled LDS y-tile ----------------
__global__ __launch_bounds__(256) void k_conv(const unsigned short* __restrict__ xt,
                                              const unsigned short* __restrict__ rt,
                                              const unsigned short* __restrict__ Wb,
                                              const float* __restrict__ bias,
                                              float* __restrict__ out) {
    __shared__ __align__(16) unsigned short ytile[64 * TWOC_];   // 48 KiB
    char* yb = (char*)ytile;

    int bid  = blockIdx.x;               // 512
    int xcd  = bid & 7;
    int b    = xcd >> 1;
    int slot = bid >> 3;                 // 0..63
    int n0   = ((xcd & 1) * 64 + slot) * 64;

    int tid  = threadIdx.x;
    int wave = tid >> 6;
    int lane = tid & 63;
    int m16  = lane & 15;
    int quad = lane >> 4;

    const unsigned short* xsrc = xt + ((size_t)b * N_ + n0) * C_;
    const unsigned short* rsrc = rt + ((size_t)b * N_ + n0) * C_;
#pragma unroll
    for (int i = 0; i < 6; i++) {
        int id = i * 256 + tid;          // 0..1535
        int row = id / 24, chunk = id % 24;
        int sw = (row & 7) << 4;
        half8 vx = *(const half8*)(xsrc + (size_t)row * C_ + chunk * 8);
        half8 vr = *(const half8*)(rsrc + (size_t)row * C_ + chunk * 8);
        *(half8*)(yb + row * 768 + ((chunk * 16) ^ sw))       = vx;
        *(half8*)(yb + row * 768 + 384 + ((chunk * 16) ^ sw)) = vr;
    }
    __syncthreads();

    const unsigned short* wbase = Wb + (size_t)(wave * 48 + m16) * TWOC_ + quad * 8;

    floatx4 acc[3][4];
#pragma unroll
    for (int i = 0; i < 3; i++)
#pragma unroll
        for (int j = 0; j < 4; j++) acc[i][j] = (floatx4){0.f, 0.f, 0.f, 0.f};

#pragma unroll 2
    for (int kt = 0; kt < 12; kt++) {
        half8 wf[3], yf[4];
#pragma unroll
        for (int i = 0; i < 3; i++)
            wf[i] = *(const half8*)(wbase + (size_t)(i * 16) * TWOC_ + kt * 32);
#pragma unroll
        for (int j = 0; j < 4; j++) {
            int row = j * 16 + m16;
            yf[j] = *(const half8*)(yb + row * 768 + ((kt * 64 + quad * 16) ^ ((row & 7) << 4)));
        }
#pragma unroll
        for (int i = 0; i < 3; i++)
#pragma unroll
            for (int j = 0; j < 4; j++)
                acc[i][j] = __builtin_amdgcn_mfma_f32_16x16x32_f16(wf[i], yf[j], acc[i][j], 0, 0, 0);
    }

#pragma unroll
    for (int i = 0; i < 3; i++) {
#pragma unroll
        for (int r = 0; r < 4; r++) {
            int o = wave * 48 + i * 16 + quad * 4 + r;
            float bv = bias[o];
#pragma unroll
            for (int j = 0; j < 4; j++) {
                int n = n0 + j * 16 + m16;
                __builtin_nontemporal_store(fmaxf(acc[i][j][r] + bv, 0.f),
                                            &out[((size_t)b * O_ + o) * N_ + n]);
            }
        }
    }
}

extern "C" void kernel_launch(void* const* d_in, const int* in_sizes, int n_in,
                              void* d_out, int out_size, void* d_ws, size_t ws_size,
                              hipStream_t stream) {
    const float* x    = (const float*)d_in[0];
    const int*   eidx = (const int*)d_in[2];
    const float* W    = (const float*)d_in[3];
    const float* bias = (const float*)d_in[4];
    float*       out  = (float*)d_out;

    unsigned short* Wb = (unsigned short*)d_ws;                       // 147456 B
    unsigned short* xt = (unsigned short*)((char*)d_ws + 147456);     // 12.58 MB  [b,n,192]
    unsigned short* xg = (unsigned short*)((char*)d_ws + 12730368);   // 12.58 MB  [b,48,N,4]
    unsigned short* rt = (unsigned short*)((char*)d_ws + 25313280);   // 12.58 MB  [b,n,192]

    k_prep<<<dim3(6162), dim3(256), 0, stream>>>(x, W, xt, xg, Wb);
    k_gather<<<dim3(384), dim3(256), 0, stream>>>(xg, eidx, rt);
    k_conv<<<dim3(512), dim3(256), 0, stream>>>(xt, rt, Wb, bias, out);
}

// Round 9
// 134.011 us; speedup vs baseline: 1.1713x; 1.1713x over previous
//
#include <hip/hip_runtime.h>
#include <hip/hip_fp16.h>

#define B_    4
#define C_    192
#define N_    8192
#define K_    16
#define O_    192
#define TWOC_ 384
#define BN_   (B_ * N_)
#define NSL_  48   // 4-channel slices

typedef __attribute__((ext_vector_type(8))) _Float16 half8;
typedef __attribute__((ext_vector_type(4))) _Float16 half4v;
typedef __attribute__((ext_vector_type(4))) float floatx4;
typedef __attribute__((ext_vector_type(4))) float fvec4;
typedef __attribute__((ext_vector_type(4))) int   ivec4;
typedef __attribute__((ext_vector_type(4))) unsigned int uvec4;
typedef __attribute__((ext_vector_type(2))) unsigned int uvec2;

// ---------------- K1: prep ----------------
// blocks 0..6143: 32x32 transpose tiles -> xg[b,48,N,4] fp16 (slice-major,
// node-contiguous 8B units). blocks 6144..6161: W -> fp16.
__global__ __launch_bounds__(256) void k_prep(const float* __restrict__ x,
                                              const float* __restrict__ W,
                                              unsigned short* __restrict__ xg,
                                              unsigned short* __restrict__ Wb) {
    int bid = blockIdx.x;
    int tid = threadIdx.x;

    if (bid >= 6144) {
        int base = ((bid - 6144) * 256 + tid) * 16;
        union { unsigned short u[16]; uvec4 v[2]; } o;
#pragma unroll
        for (int q = 0; q < 16; q += 4) {
            fvec4 f = __builtin_nontemporal_load((const fvec4*)(W + base + q));
            union { _Float16 h; unsigned short s; } c;
            c.h = (_Float16)f.x; o.u[q + 0] = c.s;
            c.h = (_Float16)f.y; o.u[q + 1] = c.s;
            c.h = (_Float16)f.z; o.u[q + 2] = c.s;
            c.h = (_Float16)f.w; o.u[q + 3] = c.s;
        }
        *(uvec4*)(Wb + base)     = o.v[0];
        *(uvec4*)(Wb + base + 8) = o.v[1];
        return;
    }

    __shared__ float tile[32][33];
    int xcd  = bid & 7;
    int b    = xcd >> 1;
    int half = xcd & 1;
    int slot = bid >> 3;
    int ct   = slot >> 7;                // 0..5 -> slices ct*8 .. ct*8+7
    int nt   = half * 128 + (slot & 127);
    int c0 = ct * 32, n0 = nt * 32;

    int cc  = tid >> 3;
    int nn4 = (tid & 7) * 4;
    const float* xp = x + ((size_t)b * C_ + c0 + cc) * N_ + n0 + nn4;
    fvec4 v = __builtin_nontemporal_load((const fvec4*)xp);
    tile[nn4 + 0][cc] = v.x;
    tile[nn4 + 1][cc] = v.y;
    tile[nn4 + 2][cc] = v.z;
    tile[nn4 + 3][cc] = v.w;
    __syncthreads();

    // xg[b, slice, n, 4ch]: 8 slices x 32 rows, one 8B store per thread
    {
        int sl  = tid >> 5;              // 0..7
        int row = tid & 31;              // 0..31
        union { _Float16 h[4]; uvec2 u; } p;
#pragma unroll
        for (int c = 0; c < 4; c++) p.h[c] = (_Float16)tile[row][sl * 4 + c];
        *(uvec2*)(xg + ((size_t)(b * NSL_ + ct * 8 + sl) * N_ + n0 + row) * 4) = p.u;
    }
}

// ---------------- KG: channel-sliced LDS gather, b64 reads, coalesced feed ----------------
// 1536 blocks x 256 thr = 8 XCD-pinned (b, n-half) x 48 slices x 4 subranges.
// Stage slice (all N x 4ch, 64 KiB) -> LDS; gather 1024 nodes (4/thread,
// lane-contiguous), eidx prefetch pipelined; coalesced rt[b,48,N,4] stores.
__global__ __launch_bounds__(256) void k_gather(const unsigned short* __restrict__ xg,
                                                const int* __restrict__ eidx,
                                                unsigned short* __restrict__ rt) {
    __shared__ uvec2 lds2[N_];           // 64 KiB

    int bid  = blockIdx.x;               // 1536
    int xcd  = bid & 7;
    int b    = xcd >> 1;
    int nh   = xcd & 1;
    int rest = bid >> 3;                 // 0..191
    int s    = rest % NSL_;              // 0..47
    int sub  = rest / NSL_;              // 0..3
    int nbase = nh * 4096 + sub * 1024;
    int tid  = threadIdx.x;

    const int* e0 = eidx + (size_t)b * N_ * K_;
    const int* e1 = e0 + (size_t)BN_ * K_;

    // ---- prefetch first node's indices (lane-contiguous, coalesced) ----
    ivec4 J[4], I[4];
    {
        const int* ej = e0 + (size_t)(nbase + tid) * K_;
        const int* ei = e1 + (size_t)(nbase + tid) * K_;
#pragma unroll
        for (int q = 0; q < 4; q++) {
            J[q] = *(const ivec4*)(ej + q * 4);
            I[q] = *(const ivec4*)(ei + q * 4);
        }
    }

    // ---- stage: coalesced 16B loads, conflict-free b128 LDS writes ----
    const unsigned short* src = xg + (size_t)(b * NSL_ + s) * N_ * 4;
#pragma unroll
    for (int i = 0; i < 16; i++) {
        int idx = i * 256 + tid;         // 2-node unit
        uvec4 v = *(const uvec4*)(src + (size_t)idx * 8);
        *(uvec4*)&lds2[idx * 2] = v;
    }
    __syncthreads();

    unsigned short* rto = rt + (size_t)(b * NSL_ + s) * N_ * 4;

#pragma unroll
    for (int i = 0; i < 4; i++) {
        int n = nbase + i * 256 + tid;
        // prefetch next node's indices before consuming this node's
        ivec4 Jn[4], In[4];
        if (i < 3) {
            const int* ej = e0 + (size_t)(n + 256) * K_;
            const int* ei = e1 + (size_t)(n + 256) * K_;
#pragma unroll
            for (int q = 0; q < 4; q++) {
                Jn[q] = *(const ivec4*)(ej + q * 4);
                In[q] = *(const ivec4*)(ei + q * 4);
            }
        }
        half4v m;
#pragma unroll
        for (int q = 0; q < 4; q++)
#pragma unroll
            for (int e = 0; e < 4; e++) {
                union { uvec2 u; half4v h; } jv, iv;
                jv.u = lds2[J[q][e]];
                iv.u = lds2[I[q][e]];
                half4v d = jv.h - iv.h;
                m = (q == 0 && e == 0) ? d : __builtin_elementwise_max(m, d);
            }
        union { half4v h; uvec2 u; } o;
        o.h = m;
        *(uvec2*)(rto + (size_t)n * 4) = o.u;   // coalesced 8B/lane contiguous
#pragma unroll
        for (int q = 0; q < 4; q++) { J[q] = Jn[q]; I[q] = In[q]; }
    }
}

// ---------------- KC: 1x1 conv GEMM (fp16 MFMA), swizzled LDS y-tile ----------------
// 512 blocks x 4 waves; block = 64 nodes. Both y-halves staged from sliced
// layouts: xs from xg[b,48,N,4], rel from rt[b,48,N,4].
__global__ __launch_bounds__(256) void k_conv(const unsigned short* __restrict__ xg,
                                              const unsigned short* __restrict__ rt,
                                              const unsigned short* __restrict__ Wb,
                                              const float* __restrict__ bias,
                                              float* __restrict__ out) {
    __shared__ __align__(16) unsigned short ytile[64 * TWOC_];   // 48 KiB
    char* yb = (char*)ytile;

    int bid  = blockIdx.x;               // 512
    int xcd  = bid & 7;
    int b    = xcd >> 1;
    int slot = bid >> 3;                 // 0..63
    int n0   = ((xcd & 1) * 64 + slot) * 64;

    int tid  = threadIdx.x;
    int wave = tid >> 6;
    int lane = tid & 63;
    int m16  = lane & 15;
    int quad = lane >> 4;

    // ---- stage y = [xs | rel], both from [b,48,N,4]: 16B = 2 nodes of one slice ----
#pragma unroll
    for (int i = 0; i < 6; i++) {
        int id = i * 256 + tid;          // 0..1535
        int s  = id >> 5;                // 0..47
        int np = id & 31;                // node-pair 0..31
        int r1 = np * 2, r2 = np * 2 + 1;
        size_t goff = ((size_t)(b * NSL_ + s) * N_ + n0 + r1) * 4;
        uvec4 vx = *(const uvec4*)(xg + goff);
        uvec4 vr = *(const uvec4*)(rt + goff);
        uvec2 x1 = {vx.x, vx.y}, x2 = {vx.z, vx.w};
        uvec2 r1v = {vr.x, vr.y}, r2v = {vr.z, vr.w};
        int sw1 = (r1 & 7) << 4, sw2 = (r2 & 7) << 4;
        *(uvec2*)(yb + r1 * 768 + ((s * 8) ^ sw1))         = x1;
        *(uvec2*)(yb + r2 * 768 + ((s * 8) ^ sw2))         = x2;
        *(uvec2*)(yb + r1 * 768 + ((384 + s * 8) ^ sw1))   = r1v;
        *(uvec2*)(yb + r2 * 768 + ((384 + s * 8) ^ sw2))   = r2v;
    }
    __syncthreads();

    const unsigned short* wbase = Wb + (size_t)(wave * 48 + m16) * TWOC_ + quad * 8;

    floatx4 acc[3][4];
#pragma unroll
    for (int i = 0; i < 3; i++)
#pragma unroll
        for (int j = 0; j < 4; j++) acc[i][j] = (floatx4){0.f, 0.f, 0.f, 0.f};

#pragma unroll 2
    for (int kt = 0; kt < 12; kt++) {
        half8 wf[3], yf[4];
#pragma unroll
        for (int i = 0; i < 3; i++)
            wf[i] = *(const half8*)(wbase + (size_t)(i * 16) * TWOC_ + kt * 32);
#pragma unroll
        for (int j = 0; j < 4; j++) {
            int row = j * 16 + m16;
            yf[j] = *(const half8*)(yb + row * 768 + ((kt * 64 + quad * 16) ^ ((row & 7) << 4)));
        }
#pragma unroll
        for (int i = 0; i < 3; i++)
#pragma unroll
            for (int j = 0; j < 4; j++)
                acc[i][j] = __builtin_amdgcn_mfma_f32_16x16x32_f16(wf[i], yf[j], acc[i][j], 0, 0, 0);
    }

#pragma unroll
    for (int i = 0; i < 3; i++) {
#pragma unroll
        for (int r = 0; r < 4; r++) {
            int o = wave * 48 + i * 16 + quad * 4 + r;
            float bv = bias[o];
#pragma unroll
            for (int j = 0; j < 4; j++) {
                int n = n0 + j * 16 + m16;
                __builtin_nontemporal_store(fmaxf(acc[i][j][r] + bv, 0.f),
                                            &out[((size_t)b * O_ + o) * N_ + n]);
            }
        }
    }
}

extern "C" void kernel_launch(void* const* d_in, const int* in_sizes, int n_in,
                              void* d_out, int out_size, void* d_ws, size_t ws_size,
                              hipStream_t stream) {
    const float* x    = (const float*)d_in[0];
    const int*   eidx = (const int*)d_in[2];
    const float* W    = (const float*)d_in[3];
    const float* bias = (const float*)d_in[4];
    float*       out  = (float*)d_out;

    unsigned short* Wb = (unsigned short*)d_ws;                       // 147456 B
    unsigned short* xg = (unsigned short*)((char*)d_ws + 147456);     // 12.58 MB [b,48,N,4]
    unsigned short* rt = (unsigned short*)((char*)d_ws + 12730368);   // 12.58 MB [b,48,N,4]

    k_prep<<<dim3(6162), dim3(256), 0, stream>>>(x, W, xg, Wb);
    k_gather<<<dim3(1536), dim3(256), 0, stream>>>(xg, eidx, rt);
    k_conv<<<dim3(512), dim3(256), 0, stream>>>(xg, rt, Wb, bias, out);
}

// Round 10
// 133.062 us; speedup vs baseline: 1.1797x; 1.0071x over previous
//
#include <hip/hip_runtime.h>
#include <hip/hip_fp16.h>

#define B_    4
#define C_    192
#define N_    8192
#define K_    16
#define O_    192
#define TWOC_ 384
#define BN_   (B_ * N_)
#define NSL8_ 24   // 8-channel slices

typedef __attribute__((ext_vector_type(8))) _Float16 half8;
typedef __attribute__((ext_vector_type(4))) float floatx4;
typedef __attribute__((ext_vector_type(4))) float fvec4;
typedef __attribute__((ext_vector_type(4))) int   ivec4;
typedef __attribute__((ext_vector_type(4))) unsigned int uvec4;
typedef __attribute__((ext_vector_type(2))) unsigned int uvec2;

// ---------------- K1: prep (no LDS) ----------------
// blocks 0..3071: pack x[b, 8s..8s+8, n-chunk] fp32 -> xg[b,24,N,8] fp16.
// blocks 3072..3089: W fp32 -> fp16.
__global__ __launch_bounds__(256) void k_prep(const float* __restrict__ x,
                                              const float* __restrict__ W,
                                              unsigned short* __restrict__ xg,
                                              unsigned short* __restrict__ Wb) {
    int bid = blockIdx.x;
    int tid = threadIdx.x;

    if (bid >= 3072) {
        int base = ((bid - 3072) * 256 + tid) * 16;
        union { unsigned short u[16]; uvec4 v[2]; } o;
#pragma unroll
        for (int q = 0; q < 16; q += 4) {
            fvec4 f = __builtin_nontemporal_load((const fvec4*)(W + base + q));
            union { _Float16 h; unsigned short s; } c;
            c.h = (_Float16)f.x; o.u[q + 0] = c.s;
            c.h = (_Float16)f.y; o.u[q + 1] = c.s;
            c.h = (_Float16)f.z; o.u[q + 2] = c.s;
            c.h = (_Float16)f.w; o.u[q + 3] = c.s;
        }
        *(uvec4*)(Wb + base)     = o.v[0];
        *(uvec4*)(Wb + base + 8) = o.v[1];
        return;
    }

    // pack: bid = (xcd: b,nh) | slice s (24) | 256-node chunk (16)
    int xcd  = bid & 7;
    int b    = xcd >> 1;
    int nh   = xcd & 1;
    int rest = bid >> 3;                 // 0..383
    int s    = rest >> 4;                // 0..23
    int chunk= rest & 15;                // 0..15
    int n    = nh * 4096 + chunk * 256 + tid;

    const float* xb = x + ((size_t)b * C_ + s * 8) * N_ + n;
    union { _Float16 h[8]; uvec4 u; } p;
#pragma unroll
    for (int c = 0; c < 8; c++)
        p.h[c] = (_Float16)__builtin_nontemporal_load(xb + (size_t)c * N_);
    *(uvec4*)(xg + ((size_t)(b * NSL8_ + s) * N_ + n) * 8) = p.u;
}

// ---------------- KG: 8-ch sliced LDS gather, b128 reads ----------------
// 768 blocks x 256 thr = 8 XCD-pinned (b, n-half) x 24 slices x 4 subranges.
// Stage slice (N x 8ch = 128 KiB) -> LDS; gather 1024 nodes (4/thread,
// lane-contiguous), pipelined eidx prefetch, coalesced rt[b,24,N,8] stores.
__global__ __launch_bounds__(256, 1) void k_gather(const unsigned short* __restrict__ xg,
                                                   const int* __restrict__ eidx,
                                                   unsigned short* __restrict__ rt) {
    __shared__ uvec4 lds4[N_];           // 128 KiB

    int bid  = blockIdx.x;               // 768
    int xcd  = bid & 7;
    int b    = xcd >> 1;
    int nh   = xcd & 1;
    int rest = bid >> 3;                 // 0..95
    int s    = rest >> 2;                // 0..23
    int sub  = rest & 3;                 // 0..3
    int nbase = nh * 4096 + sub * 1024;
    int tid  = threadIdx.x;

    const int* e0 = eidx + (size_t)b * N_ * K_;
    const int* e1 = e0 + (size_t)BN_ * K_;

    // ---- prefetch first node's indices (lane-contiguous, coalesced) ----
    ivec4 J[4], I[4];
    {
        const int* ej = e0 + (size_t)(nbase + tid) * K_;
        const int* ei = e1 + (size_t)(nbase + tid) * K_;
#pragma unroll
        for (int q = 0; q < 4; q++) {
            J[q] = *(const ivec4*)(ej + q * 4);
            I[q] = *(const ivec4*)(ei + q * 4);
        }
    }

    // ---- stage: coalesced 16B loads, conflict-free b128 LDS writes ----
    const unsigned short* src = xg + (size_t)(b * NSL8_ + s) * N_ * 8;
#pragma unroll
    for (int i = 0; i < 32; i++) {
        int idx = i * 256 + tid;
        lds4[idx] = *(const uvec4*)(src + (size_t)idx * 8);
    }
    __syncthreads();

    unsigned short* rto = rt + (size_t)(b * NSL8_ + s) * N_ * 8;

#pragma unroll
    for (int i = 0; i < 4; i++) {
        int n = nbase + i * 256 + tid;
        ivec4 Jn[4], In[4];
        if (i < 3) {
            const int* ej = e0 + (size_t)(n + 256) * K_;
            const int* ei = e1 + (size_t)(n + 256) * K_;
#pragma unroll
            for (int q = 0; q < 4; q++) {
                Jn[q] = *(const ivec4*)(ej + q * 4);
                In[q] = *(const ivec4*)(ei + q * 4);
            }
        }
        half8 m;
#pragma unroll
        for (int q = 0; q < 4; q++)
#pragma unroll
            for (int e = 0; e < 4; e++) {
                union { uvec4 u; half8 h; } jv, iv;
                jv.u = lds4[J[q][e]];
                iv.u = lds4[I[q][e]];
                half8 d = jv.h - iv.h;
                m = (q == 0 && e == 0) ? d : __builtin_elementwise_max(m, d);
            }
        union { half8 h; uvec4 u; } o;
        o.h = m;
        *(uvec4*)(rto + (size_t)n * 8) = o.u;   // 16B/lane contiguous
#pragma unroll
        for (int q = 0; q < 4; q++) { J[q] = Jn[q]; I[q] = In[q]; }
    }
}

// ---------------- KC: 1x1 conv GEMM (fp16 MFMA), swizzled LDS y-tile ----------------
// 512 blocks x 4 waves; block = 64 nodes. y = [xs | rel] staged from the
// 8-ch sliced layouts (16B per node-slice, 1KB contiguous runs).
__global__ __launch_bounds__(256) void k_conv(const unsigned short* __restrict__ xg,
                                              const unsigned short* __restrict__ rt,
                                              const unsigned short* __restrict__ Wb,
                                              const float* __restrict__ bias,
                                              float* __restrict__ out) {
    __shared__ __align__(16) unsigned short ytile[64 * TWOC_];   // 48 KiB
    char* yb = (char*)ytile;

    int bid  = blockIdx.x;               // 512
    int xcd  = bid & 7;
    int b    = xcd >> 1;
    int slot = bid >> 3;                 // 0..63
    int n0   = ((xcd & 1) * 64 + slot) * 64;

    int tid  = threadIdx.x;
    int wave = tid >> 6;
    int lane = tid & 63;
    int m16  = lane & 15;
    int quad = lane >> 4;

    // ---- stage y-tile: 1536 units = 24 slices x 64 nodes, 16B each ----
#pragma unroll
    for (int i = 0; i < 6; i++) {
        int id  = i * 256 + tid;         // 0..1535
        int s   = id >> 6;               // 0..23
        int node= id & 63;               // 0..63
        size_t goff = ((size_t)(b * NSL8_ + s) * N_ + n0 + node) * 8;
        uvec4 vx = *(const uvec4*)(xg + goff);
        uvec4 vr = *(const uvec4*)(rt + goff);
        int sw = (node & 7) << 4;
        *(uvec4*)(yb + node * 768 + ((s * 16) ^ sw))         = vx;
        *(uvec4*)(yb + node * 768 + ((384 + s * 16) ^ sw))   = vr;
    }
    __syncthreads();

    const unsigned short* wbase = Wb + (size_t)(wave * 48 + m16) * TWOC_ + quad * 8;

    floatx4 acc[3][4];
#pragma unroll
    for (int i = 0; i < 3; i++)
#pragma unroll
        for (int j = 0; j < 4; j++) acc[i][j] = (floatx4){0.f, 0.f, 0.f, 0.f};

#pragma unroll 2
    for (int kt = 0; kt < 12; kt++) {
        half8 wf[3], yf[4];
#pragma unroll
        for (int i = 0; i < 3; i++)
            wf[i] = *(const half8*)(wbase + (size_t)(i * 16) * TWOC_ + kt * 32);
#pragma unroll
        for (int j = 0; j < 4; j++) {
            int row = j * 16 + m16;
            yf[j] = *(const half8*)(yb + row * 768 + ((kt * 64 + quad * 16) ^ ((row & 7) << 4)));
        }
#pragma unroll
        for (int i = 0; i < 3; i++)
#pragma unroll
            for (int j = 0; j < 4; j++)
                acc[i][j] = __builtin_amdgcn_mfma_f32_16x16x32_f16(wf[i], yf[j], acc[i][j], 0, 0, 0);
    }

#pragma unroll
    for (int i = 0; i < 3; i++) {
#pragma unroll
        for (int r = 0; r < 4; r++) {
            int o = wave * 48 + i * 16 + quad * 4 + r;
            float bv = bias[o];
#pragma unroll
            for (int j = 0; j < 4; j++) {
                int n = n0 + j * 16 + m16;
                __builtin_nontemporal_store(fmaxf(acc[i][j][r] + bv, 0.f),
                                            &out[((size_t)b * O_ + o) * N_ + n]);
            }
        }
    }
}

extern "C" void kernel_launch(void* const* d_in, const int* in_sizes, int n_in,
                              void* d_out, int out_size, void* d_ws, size_t ws_size,
                              hipStream_t stream) {
    const float* x    = (const float*)d_in[0];
    const int*   eidx = (const int*)d_in[2];
    const float* W    = (const float*)d_in[3];
    const float* bias = (const float*)d_in[4];
    float*       out  = (float*)d_out;

    unsigned short* Wb = (unsigned short*)d_ws;                       // 147456 B
    unsigned short* xg = (unsigned short*)((char*)d_ws + 147456);     // 12.58 MB [b,24,N,8]
    unsigned short* rt = (unsigned short*)((char*)d_ws + 12730368);   // 12.58 MB [b,24,N,8]

    k_prep<<<dim3(3090), dim3(256), 0, stream>>>(x, W, xg, Wb);
    k_gather<<<dim3(768), dim3(256), 0, stream>>>(xg, eidx, rt);
    k_conv<<<dim3(512), dim3(256), 0, stream>>>(xg, rt, Wb, bias, out);
}